// Round 11
// baseline (504.015 us; speedup 1.0000x reference)
//
#include <hip/hip_runtime.h>

typedef unsigned short u16;
typedef __attribute__((ext_vector_type(8))) __bf16 bf16x8;
typedef __attribute__((ext_vector_type(4))) float f32x4;

// Problem constants
#define BB 4
#define TT 2048
#define EE 2048
#define HH 16
#define KVH 4
#define DD 128
// KVb: (B*T, 1024): cols [0,512) = K heads, [512,1024) = V heads

static __device__ __forceinline__ u16 f2bf(float f) {
  unsigned int u = __float_as_uint(f);
  u += 0x7fffu + ((u >> 16) & 1u);
  return (u16)(u >> 16);
}

// async global->LDS, 16B per lane. LDS dest is wave-uniform base + lane*16;
// all call sites pass per-lane pointers that are linear in lane with stride 16B.
static __device__ __forceinline__ void gl_lds16(const u16* g, u16* l) {
  __builtin_amdgcn_global_load_lds((__attribute__((address_space(1))) void*)g,
                                   (__attribute__((address_space(3))) void*)l,
                                   16, 0, 0);
}

// ---------------- fp32 -> bf16 convert ----------------
__global__ __launch_bounds__(256) void cvt_f32_bf16(const float* __restrict__ in,
                                                    u16* __restrict__ out, int n4) {
  int i = blockIdx.x * 256 + threadIdx.x;
  if (i >= n4) return;
  float4 v = ((const float4*)in)[i];
  union { uint2 u2; u16 s[4]; } o;
  o.s[0] = f2bf(v.x); o.s[1] = f2bf(v.y); o.s[2] = f2bf(v.z); o.s[3] = f2bf(v.w);
  ((uint2*)out)[i] = o.u2;
}

// ---------------- W (R x C) fp32 -> W^T (C x R) bf16 ----------------
__global__ __launch_bounds__(256) void transpose_w(const float* __restrict__ W,
                                                   u16* __restrict__ Wt, int R, int C) {
  __shared__ float tile[32][33];
  int tx = threadIdx.x & 31, ty = threadIdx.x >> 5;
  int r0 = blockIdx.y * 32, c0 = blockIdx.x * 32;
  #pragma unroll
  for (int i = ty; i < 32; i += 8)
    tile[i][tx] = W[(size_t)(r0 + i) * C + (c0 + tx)];
  __syncthreads();
  #pragma unroll
  for (int i = ty; i < 32; i += 8)
    Wt[(size_t)(c0 + i) * R + (r0 + tx)] = f2bf(tile[tx][i]);
}

// ---------------- V (bf16, token-major) -> VTg (d-major) ----------------
__global__ __launch_bounds__(256) void transpose_v(const u16* __restrict__ KVb,
                                                   u16* __restrict__ VTg) {
  __shared__ u16 tile[32][36];
  const int tid = threadIdx.x;
  const int t0 = blockIdx.x * 32, d0 = blockIdx.y * 32;
  const int z = blockIdx.z;                       // b*4 + kvh
  const int vb = z * 128;
  const size_t srcbase = (size_t)(z >> 2) * TT * 1024 + 512 + (z & 3) * 128;
  {
    int i = tid >> 3, c4 = (tid & 7) * 4;
    union { uint2 u; u16 s[4]; } r;
    r.u = *(const uint2*)(KVb + srcbase + (size_t)(t0 + i) * 1024 + d0 + c4);
    tile[i][c4] = r.s[0]; tile[i][c4 + 1] = r.s[1];
    tile[i][c4 + 2] = r.s[2]; tile[i][c4 + 3] = r.s[3];
  }
  __syncthreads();
  {
    int j = tid >> 3, cc = (tid & 7) * 4;
    union { uint2 u; u16 s[4]; } w;
    w.s[0] = tile[cc][j]; w.s[1] = tile[cc + 1][j];
    w.s[2] = tile[cc + 2][j]; w.s[3] = tile[cc + 3][j];
    *(uint2*)(VTg + (size_t)(vb + d0 + j) * TT + t0 + cc) = w.u;
  }
}

// ---------------- 256x256 8-phase bf16 GEMM (T1+T2+T3+T4+T5) --------------
// (unchanged — refcheck'd)
template <int MODE>
__global__ __launch_bounds__(512) void gemm256(const u16* __restrict__ A,
                                               const u16* __restrict__ Bt0,
                                               const u16* __restrict__ Bt1,
                                               void* __restrict__ C0,
                                               void* __restrict__ C1,
                                               int M, int N0, int N1, int K, int nbx) {
  __shared__ __align__(16) u16 sh[2][4][8192];  // [buf][A0,A1,B0,B1][128*64]
  const int tid = threadIdx.x;
  const int lane = tid & 63, wave = tid >> 6;
  const int quad = lane >> 4, n16 = lane & 15;
  const int mi = wave >> 2, ni = wave & 3;

  const int nwg = gridDim.x;
  int wg = blockIdx.x;
  wg = (wg & 7) * (nwg >> 3) + (wg >> 3);
  const int bx = wg % nbx, by = wg / nbx;
  const size_t rowbase = (size_t)by * 256;
  const int colbase = bx * 256;

  const u16* Bt = Bt0;
  int bcol = colbase;
  if (MODE == 1 && colbase >= N0) { Bt = Bt1; bcol = colbase - N0; }

  const int c0 = tid, c1 = tid + 512;
  const int r0s = c0 >> 3, ci0 = (c0 & 7) ^ (r0s & 7);
  const int r1s = c1 >> 3, ci1 = (c1 & 7) ^ (r1s & 7);
  const u16* Ag0 = A + (rowbase + r0s) * (size_t)K + ci0 * 8;
  const u16* Ag1 = A + (rowbase + r1s) * (size_t)K + ci1 * 8;
  const u16* Bg0 = Bt + ((size_t)bcol + r0s) * K + ci0 * 8;
  const u16* Bg1 = Bt + ((size_t)bcol + r1s) * K + ci1 * 8;
  const size_t h128K = (size_t)128 * K;

#define STAGE(ob, h, kb) do {                                              \
    if ((h) < 2) {                                                         \
      gl_lds16(Ag0 + (size_t)(h) * h128K + (kb), &sh[ob][h][c0 * 8]);      \
      gl_lds16(Ag1 + (size_t)(h) * h128K + (kb), &sh[ob][h][c1 * 8]);      \
    } else {                                                               \
      gl_lds16(Bg0 + (size_t)((h) - 2) * h128K + (kb), &sh[ob][h][c0 * 8]);\
      gl_lds16(Bg1 + (size_t)((h) - 2) * h128K + (kb), &sh[ob][h][c1 * 8]);\
    } } while (0)

#define LDA_HALF(mh) do {                                                  \
    _Pragma("unroll") for (int m = 0; m < 4; ++m)                          \
      _Pragma("unroll") for (int kk = 0; kk < 2; ++kk) {                   \
        int row_ = ((mh) * 4 + m) * 16 + n16;                              \
        int c_ = row_ * 8 + ((kk * 4 + quad) ^ (n16 & 7));                 \
        af[m][kk] = *(const bf16x8*)&sh[buf][mi][c_ * 8];                  \
      } } while (0)

#define LDB_HALF(nh, BF) do {                                              \
    _Pragma("unroll") for (int n = 0; n < 2; ++n)                          \
      _Pragma("unroll") for (int kk = 0; kk < 2; ++kk) {                   \
        int row_ = (ni & 1) * 64 + ((nh) * 2 + n) * 16 + n16;              \
        int c_ = row_ * 8 + ((kk * 4 + quad) ^ (n16 & 7));                 \
        BF[n][kk] = *(const bf16x8*)&sh[buf][2 + (ni >> 1)][c_ * 8];       \
      } } while (0)

#define DO_QUAD(mh, nh, BF) do {                                           \
    __builtin_amdgcn_s_setprio(1);                                         \
    _Pragma("unroll") for (int m = 0; m < 4; ++m)                          \
      _Pragma("unroll") for (int n = 0; n < 2; ++n)                        \
        _Pragma("unroll") for (int kk = 0; kk < 2; ++kk)                   \
          acc[(mh) * 4 + m][(nh) * 2 + n] =                                \
              __builtin_amdgcn_mfma_f32_16x16x32_bf16(                     \
                  af[m][kk], BF[n][kk], acc[(mh) * 4 + m][(nh) * 2 + n],   \
                  0, 0, 0);                                                \
    __builtin_amdgcn_s_setprio(0);                                         \
  } while (0)

#define FENCE() asm volatile("" ::: "memory")

  f32x4 acc[8][4];
  #pragma unroll
  for (int i = 0; i < 8; ++i)
    #pragma unroll
    for (int j = 0; j < 4; ++j) acc[i][j] = (f32x4){0.f, 0.f, 0.f, 0.f};

  bf16x8 af[4][2], bf0[2][2], bf1[2][2];
  const int nt = K / 64;

  STAGE(0, 0, 0); STAGE(0, 1, 0); STAGE(0, 2, 0); STAGE(0, 3, 0);

  #pragma unroll 2
  for (int t = 0; t < nt; ++t) {
    const int buf = t & 1, ob = buf ^ 1;
    const int kbn = (t + 1) * 64;
    const bool pre = (t + 1 < nt);

    if (pre) {
      STAGE(ob, 0, kbn);
      asm volatile("s_waitcnt vmcnt(2)" ::: "memory");
    } else {
      asm volatile("s_waitcnt vmcnt(0)" ::: "memory");
    }
    __builtin_amdgcn_s_barrier(); FENCE();
    LDA_HALF(0); LDB_HALF(0, bf0);
    DO_QUAD(0, 0, bf0);
    __builtin_amdgcn_s_barrier(); FENCE();

    LDB_HALF(1, bf1);
    if (pre) STAGE(ob, 1, kbn);
    __builtin_amdgcn_s_barrier(); FENCE();
    DO_QUAD(0, 1, bf1);
    __builtin_amdgcn_s_barrier(); FENCE();

    LDA_HALF(1);
    if (pre) STAGE(ob, 2, kbn);
    __builtin_amdgcn_s_barrier(); FENCE();
    DO_QUAD(1, 1, bf1);
    __builtin_amdgcn_s_barrier(); FENCE();

    if (pre) STAGE(ob, 3, kbn);
    __builtin_amdgcn_s_barrier(); FENCE();
    DO_QUAD(1, 0, bf0);
    __builtin_amdgcn_s_barrier(); FENCE();
  }

#undef STAGE
#undef LDA_HALF
#undef LDB_HALF
#undef DO_QUAD
#undef FENCE

  const size_t crow0 = rowbase + (size_t)mi * 128;
  #pragma unroll
  for (int mt = 0; mt < 8; ++mt) {
    #pragma unroll
    for (int r = 0; r < 4; ++r) {
      size_t row = crow0 + mt * 16 + quad * 4 + r;
      #pragma unroll
      for (int nt_ = 0; nt_ < 4; ++nt_) {
        int col = colbase + ni * 64 + nt_ * 16 + n16;
        float v = acc[mt][nt_][r];
        if (MODE == 0) {
          ((float*)C0)[row * (size_t)N0 + col] = v;
        } else {
          if (col < N0) ((u16*)C0)[row * (size_t)N0 + col] = f2bf(v);
          else          ((u16*)C1)[row * (size_t)N1 + (col - N0)] = f2bf(v);
        }
      }
    }
  }
}

// ---------------- flash attention (causal, GQA), no-max softmax ------------
// Round-11: occupancy restructure. R10 body retained verbatim (f2bf scalar,
// ternary mask, s_waitcnt(0) P-wait, single-buffer + __syncthreads, Vt XOR
// swizzle). Blocks halved to 64 q-rows (wave = 16 rows, mt dim deleted) so
// 4 blocks/CU fit (LDS ~21.5K, VGPR ~96 <= 128); grid (16,64) = 1024 blocks
// = exact 4/CU x 256. Balanced 2-pass pairing qt = bx then 31-bx -> every
// block does exactly 66 k-tiles (homogeneous — round-3's heterogeneity trap
// designed out). Mechanism: R10 showed VALU 51% + MFMA 20% at 2 waves/SIMD;
// ~29% dual-idle barrier/lgkm stall needs more resident waves (m114).
__global__ __launch_bounds__(256) void attn_kernel(const u16* __restrict__ Qm,
                                                   const u16* __restrict__ KVm,
                                                   const u16* __restrict__ VTg,
                                                   u16* __restrict__ Ym) {
  __shared__ u16 Ks[32 * 128];
  __shared__ u16 Vt[128 * 32];
  __shared__ u16 Pb[4 * 16 * 40];

  const int tid = threadIdx.x;
  const int lane = tid & 63, wave = tid >> 6;
  const int quad = lane >> 4, n16 = lane & 15;
  const int b = blockIdx.y >> 4, h = blockIdx.y & 15;
  const int kvh = h >> 2;
  const int kvbase = b * TT;
  const u16* VTg_ = VTg + (size_t)((b * 4 + kvh) * 128) * TT;

  // K staging: XOR-16 chunk swizzle (conflict-free verified)
  const int krow = tid >> 4, kslot = tid & 15;
  const int kg = (kslot ^ krow) * 8;
  u16* Ksd0 = &Ks[krow * 128 + kslot * 8];      // byte = tid*16 (linear dest)
  u16* Ksd1 = &Ks[(krow + 16) * 128 + kslot * 8];
  // V staging: swizzle ci^((row>>1)&3); linear LDS dest, source carries swizzle.
  const int vrow = tid >> 2, vs = tid & 3;
  const int vq8 = (vs ^ ((tid >> 3) & 3)) * 8;
  u16* Vtd0 = &Vt[vrow * 32 + vs * 8];
  u16* Vtd1 = &Vt[(vrow + 64) * 32 + vs * 8];

  constexpr float SCL = 0.08838834764831843f * 1.4426950408889634f;

  for (int pass = 0; pass < 2; ++pass) {
    const int qt = pass ? 31 - (int)blockIdx.x : (int)blockIdx.x;  // bx 0..15
    const int q0 = qt * 64;
    const size_t qrowbase = (size_t)(b * TT + q0);
    const int wq0 = wave * 16;

    // Q A-frags: 1 m-tile x 4 d-chunks
    bf16x8 aq[4];
    {
      const u16* qp = Qm + (qrowbase + wq0 + n16) * (HH * DD) + h * DD + quad * 8;
      #pragma unroll
      for (int dt = 0; dt < 4; ++dt)
        aq[dt] = *(const bf16x8*)(qp + dt * 32);
    }

    float lrow[4];
    f32x4 oacc[8];
    #pragma unroll
    for (int r = 0; r < 4; ++r) lrow[r] = 0.f;
    #pragma unroll
    for (int i = 0; i < 8; ++i) oacc[i] = (f32x4){0.f, 0.f, 0.f, 0.f};

    const int kend = q0 + 64;
    for (int kb = 0; kb < kend; kb += 32) {
      __syncthreads();
      gl_lds16(KVm + (size_t)(kvbase + kb + krow) * 1024 + kvh * DD + kg, Ksd0);
      gl_lds16(KVm + (size_t)(kvbase + kb + krow + 16) * 1024 + kvh * DD + kg, Ksd1);
      gl_lds16(VTg_ + (size_t)vrow * TT + kb + vq8, Vtd0);
      gl_lds16(VTg_ + (size_t)(vrow + 64) * TT + kb + vq8, Vtd1);
      __syncthreads();

      // S = Q K^T : 2 key-halves, K-frags shared
      f32x4 sf[2];
      #pragma unroll
      for (int half = 0; half < 2; ++half) {
        bf16x8 bk[4];
        #pragma unroll
        for (int dt = 0; dt < 4; ++dt) {
          int slot = (dt * 4 + quad) ^ n16;   // un-swizzle
          bk[dt] = *(const bf16x8*)&Ks[(half * 16 + n16) * 128 + slot * 8];
        }
        f32x4 s = (f32x4){0.f, 0.f, 0.f, 0.f};
        #pragma unroll
        for (int dt = 0; dt < 4; ++dt)
          s = __builtin_amdgcn_mfma_f32_16x16x32_bf16(aq[dt], bk[dt], s, 0, 0, 0);
        sf[half] = s;
      }

      // p = exp2(s*scale*log2e) with causal mask; accumulate per-lane l; stash P
      u16* pw = &Pb[wave * (16 * 40)];
      #pragma unroll
      for (int half = 0; half < 2; ++half) {
        int key = kb + half * 16 + n16;
        #pragma unroll
        for (int r = 0; r < 4; ++r) {
          int qpos = q0 + wq0 + quad * 4 + r;
          float pv = (key <= qpos) ? exp2f(sf[half][r] * SCL) : 0.f;
          lrow[r] += pv;
          pw[(quad * 4 + r) * 40 + half * 16 + n16] = f2bf(pv);
        }
      }
      __builtin_amdgcn_s_waitcnt(0);  // drain ds_writes before same-wave cross-lane read
      bf16x8 ap = *(const bf16x8*)&pw[n16 * 40 + quad * 8];

      // O += P V : swizzled V-frag reads
      #pragma unroll
      for (int dt = 0; dt < 8; ++dt) {
        bf16x8 bv = *(const bf16x8*)&Vt[(dt * 16 + n16) * 32 +
                                        ((quad ^ ((n16 >> 1) & 3)) * 8)];
        oacc[dt] = __builtin_amdgcn_mfma_f32_16x16x32_bf16(ap, bv, oacc[dt], 0, 0, 0);
      }
    }

    // epilogue: reduce l across the 16 key-lanes, normalize, store
    float rinv[4];
    #pragma unroll
    for (int r = 0; r < 4; ++r) {
      float v = lrow[r];
      v += __shfl_xor(v, 1, 64);
      v += __shfl_xor(v, 2, 64);
      v += __shfl_xor(v, 4, 64);
      v += __shfl_xor(v, 8, 64);
      rinv[r] = 1.0f / v;
    }
    #pragma unroll
    for (int dt = 0; dt < 8; ++dt)
      #pragma unroll
      for (int r = 0; r < 4; ++r) {
        size_t row = qrowbase + wq0 + quad * 4 + r;
        Ym[row * (HH * DD) + h * DD + dt * 16 + n16] = f2bf(oacc[dt][r] * rinv[r]);
      }
  }
}

// ---------------- launch ----------------
extern "C" void kernel_launch(void* const* d_in, const int* in_sizes, int n_in,
                              void* d_out, int out_size, void* d_ws, size_t ws_size,
                              hipStream_t stream) {
  const float* x  = (const float*)d_in[0];
  const float* Wq = (const float*)d_in[1];
  const float* Wk = (const float*)d_in[2];
  const float* Wv = (const float*)d_in[3];
  const float* Wo = (const float*)d_in[4];
  float* out = (float*)d_out;

  u16* ws   = (u16*)d_ws;
  u16* xb   = ws;                                  // 8192*2048 u16 (32 MiB)
  u16* Wbuf = xb + (size_t)8192 * 2048;            // 2048*2048 u16 (8 MiB)
  u16* Yb   = xb;                                  // alias: xb dead after QKV GEMM

  u16* ob   = (u16*)d_out;
  u16* Qb   = ob;                                                  // 32 MiB
  u16* KVb  = ob + (size_t)8192 * 2048;                            // 16 MiB
  u16* VTg  = ob + (size_t)8192 * 2048 + (size_t)8192 * 1024;      // 8 MiB
  u16* WkvT = VTg + (size_t)16 * 128 * 2048;                       // 4 MiB (1024x2048)

  cvt_f32_bf16<<<16384, 256, 0, stream>>>(x, xb, (4 * 2048 * 2048) / 4);

  transpose_w<<<dim3(64, 64), 256, 0, stream>>>(Wq, Wbuf, 2048, 2048);
  transpose_w<<<dim3(16, 64), 256, 0, stream>>>(Wk, WkvT, 2048, 512);
  transpose_w<<<dim3(16, 64), 256, 0, stream>>>(Wv, WkvT + (size_t)512 * 2048, 2048, 512);

  // fused [Q | KV] = x [Wq | Wk | Wv]   (N = 3072, grid 384)
  gemm256<1><<<384, 512, 0, stream>>>(xb, Wbuf, WkvT, (void*)Qb, (void*)KVb,
                                      8192, 2048, 1024, 2048, 12);

  transpose_v<<<dim3(64, 4, 16), 256, 0, stream>>>(KVb, VTg);

  attn_kernel<<<dim3(16, 64), 256, 0, stream>>>(Qb, KVb, VTg, Yb);

  transpose_w<<<dim3(64, 64), 256, 0, stream>>>(Wo, Wbuf, 2048, 2048);
  gemm256<0><<<256, 512, 0, stream>>>(Yb, Wbuf, nullptr, (void*)out, nullptr,
                                      8192, 2048, 0, 2048, 8);
}

// Round 14
// 470.694 us; speedup vs baseline: 1.0708x; 1.0708x over previous
//
#include <hip/hip_runtime.h>

typedef unsigned short u16;
typedef __attribute__((ext_vector_type(8))) __bf16 bf16x8;
typedef __attribute__((ext_vector_type(4))) float f32x4;

// Problem constants
#define BB 4
#define TT 2048
#define EE 2048
#define HH 16
#define KVH 4
#define DD 128
// KVb: (B*T, 1024): cols [0,512) = K heads, [512,1024) = V heads

static __device__ __forceinline__ u16 f2bf(float f) {
  unsigned int u = __float_as_uint(f);
  u += 0x7fffu + ((u >> 16) & 1u);
  return (u16)(u >> 16);
}

// async global->LDS, 16B per lane. LDS dest is wave-uniform base + lane*16;
// all call sites pass per-lane pointers that are linear in lane with stride 16B.
static __device__ __forceinline__ void gl_lds16(const u16* g, u16* l) {
  __builtin_amdgcn_global_load_lds((__attribute__((address_space(1))) void*)g,
                                   (__attribute__((address_space(3))) void*)l,
                                   16, 0, 0);
}

// ---------------- fp32 -> bf16 convert ----------------
__global__ __launch_bounds__(256) void cvt_f32_bf16(const float* __restrict__ in,
                                                    u16* __restrict__ out, int n4) {
  int i = blockIdx.x * 256 + threadIdx.x;
  if (i >= n4) return;
  float4 v = ((const float4*)in)[i];
  union { uint2 u2; u16 s[4]; } o;
  o.s[0] = f2bf(v.x); o.s[1] = f2bf(v.y); o.s[2] = f2bf(v.z); o.s[3] = f2bf(v.w);
  ((uint2*)out)[i] = o.u2;
}

// ---------------- W (R x C) fp32 -> W^T (C x R) bf16 ----------------
__global__ __launch_bounds__(256) void transpose_w(const float* __restrict__ W,
                                                   u16* __restrict__ Wt, int R, int C) {
  __shared__ float tile[32][33];
  int tx = threadIdx.x & 31, ty = threadIdx.x >> 5;
  int r0 = blockIdx.y * 32, c0 = blockIdx.x * 32;
  #pragma unroll
  for (int i = ty; i < 32; i += 8)
    tile[i][tx] = W[(size_t)(r0 + i) * C + (c0 + tx)];
  __syncthreads();
  #pragma unroll
  for (int i = ty; i < 32; i += 8)
    Wt[(size_t)(c0 + i) * R + (r0 + tx)] = f2bf(tile[tx][i]);
}

// ---------------- V (bf16, token-major) -> VTg (d-major) ----------------
__global__ __launch_bounds__(256) void transpose_v(const u16* __restrict__ KVb,
                                                   u16* __restrict__ VTg) {
  __shared__ u16 tile[32][36];
  const int tid = threadIdx.x;
  const int t0 = blockIdx.x * 32, d0 = blockIdx.y * 32;
  const int z = blockIdx.z;                       // b*4 + kvh
  const int vb = z * 128;
  const size_t srcbase = (size_t)(z >> 2) * TT * 1024 + 512 + (z & 3) * 128;
  {
    int i = tid >> 3, c4 = (tid & 7) * 4;
    union { uint2 u; u16 s[4]; } r;
    r.u = *(const uint2*)(KVb + srcbase + (size_t)(t0 + i) * 1024 + d0 + c4);
    tile[i][c4] = r.s[0]; tile[i][c4 + 1] = r.s[1];
    tile[i][c4 + 2] = r.s[2]; tile[i][c4 + 3] = r.s[3];
  }
  __syncthreads();
  {
    int j = tid >> 3, cc = (tid & 7) * 4;
    union { uint2 u; u16 s[4]; } w;
    w.s[0] = tile[cc][j]; w.s[1] = tile[cc + 1][j];
    w.s[2] = tile[cc + 2][j]; w.s[3] = tile[cc + 3][j];
    *(uint2*)(VTg + (size_t)(vb + d0 + j) * TT + t0 + cc) = w.u;
  }
}

// ---------------- 256x256 4-phase bf16 GEMM (out-projection) --------------
// (unchanged — refcheck'd; 256 blocks = exactly 1 dispatch round)
template <int MODE>
__global__ __launch_bounds__(512) void gemm256(const u16* __restrict__ A,
                                               const u16* __restrict__ Bt0,
                                               const u16* __restrict__ Bt1,
                                               void* __restrict__ C0,
                                               void* __restrict__ C1,
                                               int M, int N0, int N1, int K, int nbx) {
  __shared__ __align__(16) u16 sh[2][4][8192];  // [buf][A0,A1,B0,B1][128*64]
  const int tid = threadIdx.x;
  const int lane = tid & 63, wave = tid >> 6;
  const int quad = lane >> 4, n16 = lane & 15;
  const int mi = wave >> 2, ni = wave & 3;

  const int nwg = gridDim.x;
  int wg = blockIdx.x;
  wg = (wg & 7) * (nwg >> 3) + (wg >> 3);
  const int bx = wg % nbx, by = wg / nbx;
  const size_t rowbase = (size_t)by * 256;
  const int colbase = bx * 256;

  const u16* Bt = Bt0;
  int bcol = colbase;
  if (MODE == 1 && colbase >= N0) { Bt = Bt1; bcol = colbase - N0; }

  const int c0 = tid, c1 = tid + 512;
  const int r0s = c0 >> 3, ci0 = (c0 & 7) ^ (r0s & 7);
  const int r1s = c1 >> 3, ci1 = (c1 & 7) ^ (r1s & 7);
  const u16* Ag0 = A + (rowbase + r0s) * (size_t)K + ci0 * 8;
  const u16* Ag1 = A + (rowbase + r1s) * (size_t)K + ci1 * 8;
  const u16* Bg0 = Bt + ((size_t)bcol + r0s) * K + ci0 * 8;
  const u16* Bg1 = Bt + ((size_t)bcol + r1s) * K + ci1 * 8;
  const size_t h128K = (size_t)128 * K;

#define STAGE(ob, h, kb) do {                                              \
    if ((h) < 2) {                                                         \
      gl_lds16(Ag0 + (size_t)(h) * h128K + (kb), &sh[ob][h][c0 * 8]);      \
      gl_lds16(Ag1 + (size_t)(h) * h128K + (kb), &sh[ob][h][c1 * 8]);      \
    } else {                                                               \
      gl_lds16(Bg0 + (size_t)((h) - 2) * h128K + (kb), &sh[ob][h][c0 * 8]);\
      gl_lds16(Bg1 + (size_t)((h) - 2) * h128K + (kb), &sh[ob][h][c1 * 8]);\
    } } while (0)

#define LDA_HALF(mh) do {                                                  \
    _Pragma("unroll") for (int m = 0; m < 4; ++m)                          \
      _Pragma("unroll") for (int kk = 0; kk < 2; ++kk) {                   \
        int row_ = ((mh) * 4 + m) * 16 + n16;                              \
        int c_ = row_ * 8 + ((kk * 4 + quad) ^ (n16 & 7));                 \
        af[m][kk] = *(const bf16x8*)&sh[buf][mi][c_ * 8];                  \
      } } while (0)

#define LDB_HALF(nh, BF) do {                                              \
    _Pragma("unroll") for (int n = 0; n < 2; ++n)                          \
      _Pragma("unroll") for (int kk = 0; kk < 2; ++kk) {                   \
        int row_ = (ni & 1) * 64 + ((nh) * 2 + n) * 16 + n16;              \
        int c_ = row_ * 8 + ((kk * 4 + quad) ^ (n16 & 7));                 \
        BF[n][kk] = *(const bf16x8*)&sh[buf][2 + (ni >> 1)][c_ * 8];       \
      } } while (0)

#define DO_QUAD(mh, nh, BF) do {                                           \
    __builtin_amdgcn_s_setprio(1);                                         \
    _Pragma("unroll") for (int m = 0; m < 4; ++m)                          \
      _Pragma("unroll") for (int n = 0; n < 2; ++n)                        \
        _Pragma("unroll") for (int kk = 0; kk < 2; ++kk)                   \
          acc[(mh) * 4 + m][(nh) * 2 + n] =                                \
              __builtin_amdgcn_mfma_f32_16x16x32_bf16(                     \
                  af[m][kk], BF[n][kk], acc[(mh) * 4 + m][(nh) * 2 + n],   \
                  0, 0, 0);                                                \
    __builtin_amdgcn_s_setprio(0);                                         \
  } while (0)

#define FENCE() asm volatile("" ::: "memory")

  f32x4 acc[8][4];
  #pragma unroll
  for (int i = 0; i < 8; ++i)
    #pragma unroll
    for (int j = 0; j < 4; ++j) acc[i][j] = (f32x4){0.f, 0.f, 0.f, 0.f};

  bf16x8 af[4][2], bf0[2][2], bf1[2][2];
  const int nt = K / 64;

  STAGE(0, 0, 0); STAGE(0, 1, 0); STAGE(0, 2, 0); STAGE(0, 3, 0);

  #pragma unroll 2
  for (int t = 0; t < nt; ++t) {
    const int buf = t & 1, ob = buf ^ 1;
    const int kbn = (t + 1) * 64;
    const bool pre = (t + 1 < nt);

    if (pre) {
      STAGE(ob, 0, kbn);
      asm volatile("s_waitcnt vmcnt(2)" ::: "memory");
    } else {
      asm volatile("s_waitcnt vmcnt(0)" ::: "memory");
    }
    __builtin_amdgcn_s_barrier(); FENCE();
    LDA_HALF(0); LDB_HALF(0, bf0);
    DO_QUAD(0, 0, bf0);
    __builtin_amdgcn_s_barrier(); FENCE();

    LDB_HALF(1, bf1);
    if (pre) STAGE(ob, 1, kbn);
    __builtin_amdgcn_s_barrier(); FENCE();
    DO_QUAD(0, 1, bf1);
    __builtin_amdgcn_s_barrier(); FENCE();

    LDA_HALF(1);
    if (pre) STAGE(ob, 2, kbn);
    __builtin_amdgcn_s_barrier(); FENCE();
    DO_QUAD(1, 1, bf1);
    __builtin_amdgcn_s_barrier(); FENCE();

    if (pre) STAGE(ob, 3, kbn);
    __builtin_amdgcn_s_barrier(); FENCE();
    DO_QUAD(1, 0, bf0);
    __builtin_amdgcn_s_barrier(); FENCE();
  }

#undef STAGE
#undef LDA_HALF
#undef LDB_HALF
#undef DO_QUAD
#undef FENCE

  const size_t crow0 = rowbase + (size_t)mi * 128;
  #pragma unroll
  for (int mt = 0; mt < 8; ++mt) {
    #pragma unroll
    for (int r = 0; r < 4; ++r) {
      size_t row = crow0 + mt * 16 + quad * 4 + r;
      #pragma unroll
      for (int nt_ = 0; nt_ < 4; ++nt_) {
        int col = colbase + ni * 64 + nt_ * 16 + n16;
        float v = acc[mt][nt_][r];
        if (MODE == 0) {
          ((float*)C0)[row * (size_t)N0 + col] = v;
        } else {
          if (col < N0) ((u16*)C0)[row * (size_t)N0 + col] = f2bf(v);
          else          ((u16*)C1)[row * (size_t)N1 + (col - N0)] = f2bf(v);
        }
      }
    }
  }
}

// ---------------- 256x128 4-phase bf16 GEMM (QKV projection) --------------
// Same verified skeleton as gemm256, BN=128 so the QKV grid is 24x32 = 768
// blocks = exactly 3 full dispatch rounds (the 256x256 version's 384 blocks
// ran as 256+128 -> 75% utilization on the tail round).
// 8 waves as 4(mi) x 2(ni) over 64x64 sub-tiles; LDS 96 KiB; 6 loads/thread
// per K-tile (A halves 2+2, B whole 2); vmcnt(2) counted wait as before.
template <int MODE>
__global__ __launch_bounds__(512) void gemm_n128(const u16* __restrict__ A,
                                                 const u16* __restrict__ Bt0,
                                                 const u16* __restrict__ Bt1,
                                                 void* __restrict__ C0,
                                                 void* __restrict__ C1,
                                                 int M, int N0, int N1, int K, int nbx) {
  __shared__ __align__(16) u16 sh[2][3][8192];  // [buf][A0,A1,B][128*64]
  const int tid = threadIdx.x;
  const int lane = tid & 63, wave = tid >> 6;
  const int quad = lane >> 4, n16 = lane & 15;
  const int mi = wave >> 1, ni = wave & 1;      // 4 x 2 waves, 64x64 each

  const int nwg = gridDim.x;
  int wg = blockIdx.x;
  wg = (wg & 7) * (nwg >> 3) + (wg >> 3);       // bijective: nwg % 8 == 0
  const int bx = wg % nbx, by = wg / nbx;
  const size_t rowbase = (size_t)by * 256;
  const int colbase = bx * 128;

  const u16* Bt = Bt0;
  int bcol = colbase;
  if (MODE == 1 && colbase >= N0) { Bt = Bt1; bcol = colbase - N0; }

  // staging: A-half = 128x64 u16 = 1024 chunks of 16B (2 loads/thread);
  // B tile = 128x64 = 1024 chunks (2 loads/thread). inverse XOR-8 swizzle
  // on the global source, linear LDS dest (rule 21 both-sides).
  const int c0 = tid, c1 = tid + 512;
  const int r0s = c0 >> 3, ci0 = (c0 & 7) ^ (r0s & 7);
  const int r1s = c1 >> 3, ci1 = (c1 & 7) ^ (r1s & 7);
  const u16* Ag0 = A + (rowbase + r0s) * (size_t)K + ci0 * 8;
  const u16* Ag1 = A + (rowbase + r1s) * (size_t)K + ci1 * 8;
  const u16* Bg0 = Bt + ((size_t)bcol + r0s) * K + ci0 * 8;
  const u16* Bg1 = Bt + ((size_t)bcol + r1s) * K + ci1 * 8;
  const size_t h128K = (size_t)128 * K;

#define STAGEN(ob, h, kb) do {                                             \
    if ((h) < 2) {                                                         \
      gl_lds16(Ag0 + (size_t)(h) * h128K + (kb), &sh[ob][h][c0 * 8]);      \
      gl_lds16(Ag1 + (size_t)(h) * h128K + (kb), &sh[ob][h][c1 * 8]);      \
    } else {                                                               \
      gl_lds16(Bg0 + (kb), &sh[ob][2][c0 * 8]);                            \
      gl_lds16(Bg1 + (kb), &sh[ob][2][c1 * 8]);                            \
    } } while (0)

  // A frag: global row = mi*64 + (mh*2+m)*16 + n16 -> slot mi>>1,
  // row-in-slot = (mi&1)*64 + (mh*2+m)*16 + n16
#define LDAN(mh) do {                                                      \
    _Pragma("unroll") for (int m = 0; m < 2; ++m)                          \
      _Pragma("unroll") for (int kk = 0; kk < 2; ++kk) {                   \
        int row_ = (mi & 1) * 64 + ((mh) * 2 + m) * 16 + n16;              \
        int c_ = row_ * 8 + ((kk * 4 + quad) ^ (n16 & 7));                 \
        af[m][kk] = *(const bf16x8*)&sh[buf][mi >> 1][c_ * 8];             \
      } } while (0)

  // B frag: row = ni*64 + (nh*2+n)*16 + n16 in slot 2
#define LDBN(nh, BF) do {                                                  \
    _Pragma("unroll") for (int n = 0; n < 2; ++n)                          \
      _Pragma("unroll") for (int kk = 0; kk < 2; ++kk) {                   \
        int row_ = ni * 64 + ((nh) * 2 + n) * 16 + n16;                    \
        int c_ = row_ * 8 + ((kk * 4 + quad) ^ (n16 & 7));                 \
        BF[n][kk] = *(const bf16x8*)&sh[buf][2][c_ * 8];                   \
      } } while (0)

#define QUADN(mh, nh, BF) do {                                             \
    __builtin_amdgcn_s_setprio(1);                                         \
    _Pragma("unroll") for (int m = 0; m < 2; ++m)                          \
      _Pragma("unroll") for (int n = 0; n < 2; ++n)                        \
        _Pragma("unroll") for (int kk = 0; kk < 2; ++kk)                   \
          acc[(mh) * 2 + m][(nh) * 2 + n] =                                \
              __builtin_amdgcn_mfma_f32_16x16x32_bf16(                     \
                  af[m][kk], BF[n][kk], acc[(mh) * 2 + m][(nh) * 2 + n],   \
                  0, 0, 0);                                                \
    __builtin_amdgcn_s_setprio(0);                                         \
  } while (0)

#define FENCE() asm volatile("" ::: "memory")

  f32x4 acc[4][4];
  #pragma unroll
  for (int i = 0; i < 4; ++i)
    #pragma unroll
    for (int j = 0; j < 4; ++j) acc[i][j] = (f32x4){0.f, 0.f, 0.f, 0.f};

  bf16x8 af[2][2], bf0[2][2], bf1[2][2];
  const int nt = K / 64;

  STAGEN(0, 0, 0); STAGEN(0, 1, 0); STAGEN(0, 2, 0);

  #pragma unroll 2
  for (int t = 0; t < nt; ++t) {
    const int buf = t & 1, ob = buf ^ 1;
    const int kbn = (t + 1) * 64;
    const bool pre = (t + 1 < nt);

    // at top: 6 loads of tile t outstanding; issue 2 (t+1 A0) -> 8;
    // vmcnt(2) drains the oldest 6 (tile t complete), keeps 2 in flight.
    if (pre) {
      STAGEN(ob, 0, kbn);
      asm volatile("s_waitcnt vmcnt(2)" ::: "memory");
    } else {
      asm volatile("s_waitcnt vmcnt(0)" ::: "memory");
    }
    __builtin_amdgcn_s_barrier(); FENCE();
    LDAN(0); LDBN(0, bf0);
    QUADN(0, 0, bf0);
    __builtin_amdgcn_s_barrier(); FENCE();

    LDBN(1, bf1);
    if (pre) STAGEN(ob, 1, kbn);
    __builtin_amdgcn_s_barrier(); FENCE();
    QUADN(0, 1, bf1);
    __builtin_amdgcn_s_barrier(); FENCE();

    LDAN(1);
    if (pre) STAGEN(ob, 2, kbn);
    __builtin_amdgcn_s_barrier(); FENCE();
    QUADN(1, 1, bf1);
    __builtin_amdgcn_s_barrier(); FENCE();

    __builtin_amdgcn_s_barrier(); FENCE();
    QUADN(1, 0, bf0);
    __builtin_amdgcn_s_barrier(); FENCE();
  }

#undef STAGEN
#undef LDAN
#undef LDBN
#undef QUADN
#undef FENCE

  const size_t crow0 = rowbase + (size_t)mi * 64;
  #pragma unroll
  for (int mt = 0; mt < 4; ++mt) {
    #pragma unroll
    for (int r = 0; r < 4; ++r) {
      size_t row = crow0 + mt * 16 + quad * 4 + r;
      #pragma unroll
      for (int nt_ = 0; nt_ < 4; ++nt_) {
        int col = colbase + ni * 64 + nt_ * 16 + n16;
        float v = acc[mt][nt_][r];
        if (MODE == 0) {
          ((float*)C0)[row * (size_t)N0 + col] = v;
        } else {
          if (col < N0) ((u16*)C0)[row * (size_t)N0 + col] = f2bf(v);
          else          ((u16*)C1)[row * (size_t)N1 + (col - N0)] = f2bf(v);
        }
      }
    }
  }
}

// ---------------- flash attention (causal, GQA), no-max softmax ------------
// R10-exact (measured 148.7 µs @ 20.2% occ, VGPR 112): 128 q-rows/block,
// balanced 2-pass grid (8,64); f2bf scalar casts, ternary mask, s_waitcnt(0)
// P-wait, single-buffer + __syncthreads; Vt XOR swizzle (conflicts 5.57M->1.1M).
// [R11's 64-row/block split regressed 148.7->180: staging traffic x2 and
// per-tile serial overhead outran the occupancy gain (25% not 40%).]
__global__ __launch_bounds__(256) void attn_kernel(const u16* __restrict__ Qm,
                                                   const u16* __restrict__ KVm,
                                                   const u16* __restrict__ VTg,
                                                   u16* __restrict__ Ym) {
  __shared__ u16 Ks[32 * 128];
  __shared__ u16 Vt[128 * 32];
  __shared__ u16 Pb[4 * 32 * 40];

  const int tid = threadIdx.x;
  const int lane = tid & 63, wave = tid >> 6;
  const int quad = lane >> 4, n16 = lane & 15;
  const int b = blockIdx.y >> 4, h = blockIdx.y & 15;
  const int kvh = h >> 2;
  const int kvbase = b * TT;
  const u16* VTg_ = VTg + (size_t)((b * 4 + kvh) * 128) * TT;

  // K staging: XOR-16 chunk swizzle (conflict-free verified)
  const int krow = tid >> 4, kslot = tid & 15;
  const int kg = (kslot ^ krow) * 8;
  u16* Ksd0 = &Ks[krow * 128 + kslot * 8];      // byte = tid*16 (linear dest)
  u16* Ksd1 = &Ks[(krow + 16) * 128 + kslot * 8];
  // V staging: swizzle ci^((row>>1)&3); linear LDS dest, source carries swizzle.
  const int vrow = tid >> 2, vs = tid & 3;
  const int vq8 = (vs ^ ((tid >> 3) & 3)) * 8;
  u16* Vtd0 = &Vt[vrow * 32 + vs * 8];
  u16* Vtd1 = &Vt[(vrow + 64) * 32 + vs * 8];

  constexpr float SCL = 0.08838834764831843f * 1.4426950408889634f;

  for (int pass = 0; pass < 2; ++pass) {
    const int qt = pass ? 15 - (int)blockIdx.x : (int)blockIdx.x;
    const int q0 = qt * 128;
    const size_t qrowbase = (size_t)(b * TT + q0);
    const int wq0 = wave * 32;

    bf16x8 aq[2][4];
    #pragma unroll
    for (int mt = 0; mt < 2; ++mt) {
      const u16* qp = Qm + (qrowbase + wq0 + mt * 16 + n16) * (HH * DD) + h * DD + quad * 8;
      #pragma unroll
      for (int dt = 0; dt < 4; ++dt)
        aq[mt][dt] = *(const bf16x8*)(qp + dt * 32);
    }

    float lrow[2][4];
    f32x4 oacc[2][8];
    #pragma unroll
    for (int mt = 0; mt < 2; ++mt) {
      #pragma unroll
      for (int r = 0; r < 4; ++r) lrow[mt][r] = 0.f;
      #pragma unroll
      for (int i = 0; i < 8; ++i) oacc[mt][i] = (f32x4){0.f, 0.f, 0.f, 0.f};
    }

    const int kend = q0 + 128;
    for (int kb = 0; kb < kend; kb += 32) {
      __syncthreads();
      gl_lds16(KVm + (size_t)(kvbase + kb + krow) * 1024 + kvh * DD + kg, Ksd0);
      gl_lds16(KVm + (size_t)(kvbase + kb + krow + 16) * 1024 + kvh * DD + kg, Ksd1);
      gl_lds16(VTg_ + (size_t)vrow * TT + kb + vq8, Vtd0);
      gl_lds16(VTg_ + (size_t)(vrow + 64) * TT + kb + vq8, Vtd1);
      __syncthreads();

      // S = Q K^T : 2 m-tiles x 2 key-halves, K-frags shared across m
      f32x4 sf[2][2];
      #pragma unroll
      for (int half = 0; half < 2; ++half) {
        bf16x8 bk[4];
        #pragma unroll
        for (int dt = 0; dt < 4; ++dt) {
          int slot = (dt * 4 + quad) ^ n16;   // un-swizzle
          bk[dt] = *(const bf16x8*)&Ks[(half * 16 + n16) * 128 + slot * 8];
        }
        #pragma unroll
        for (int mt = 0; mt < 2; ++mt) {
          f32x4 s = (f32x4){0.f, 0.f, 0.f, 0.f};
          #pragma unroll
          for (int dt = 0; dt < 4; ++dt)
            s = __builtin_amdgcn_mfma_f32_16x16x32_bf16(aq[mt][dt], bk[dt], s, 0, 0, 0);
          sf[mt][half] = s;
        }
      }

      // p = exp2(s*scale*log2e) with causal mask; accumulate per-lane l; stash P
      u16* pw = &Pb[wave * (32 * 40)];
      #pragma unroll
      for (int mt = 0; mt < 2; ++mt)
        #pragma unroll
        for (int half = 0; half < 2; ++half) {
          int key = kb + half * 16 + n16;
          #pragma unroll
          for (int r = 0; r < 4; ++r) {
            int qpos = q0 + wq0 + mt * 16 + quad * 4 + r;
            float pv = (key <= qpos) ? exp2f(sf[mt][half][r] * SCL) : 0.f;
            lrow[mt][r] += pv;
            pw[(mt * 16 + quad * 4 + r) * 40 + half * 16 + n16] = f2bf(pv);
          }
        }
      __builtin_amdgcn_s_waitcnt(0);  // drain ds_writes before same-wave cross-lane read
      bf16x8 ap[2];
      ap[0] = *(const bf16x8*)&pw[n16 * 40 + quad * 8];
      ap[1] = *(const bf16x8*)&pw[(16 + n16) * 40 + quad * 8];

      // O += P V : V-frags shared across m-tiles (swizzled read)
      #pragma unroll
      for (int dt = 0; dt < 8; ++dt) {
        bf16x8 bv = *(const bf16x8*)&Vt[(dt * 16 + n16) * 32 +
                                        ((quad ^ ((n16 >> 1) & 3)) * 8)];
        oacc[0][dt] = __builtin_amdgcn_mfma_f32_16x16x32_bf16(ap[0], bv, oacc[0][dt], 0, 0, 0);
        oacc[1][dt] = __builtin_amdgcn_mfma_f32_16x16x32_bf16(ap[1], bv, oacc[1][dt], 0, 0, 0);
      }
    }

    // epilogue: reduce l across the 16 key-lanes, normalize, store
    float rinv[2][4];
    #pragma unroll
    for (int mt = 0; mt < 2; ++mt)
      #pragma unroll
      for (int r = 0; r < 4; ++r) {
        float v = lrow[mt][r];
        v += __shfl_xor(v, 1, 64);
        v += __shfl_xor(v, 2, 64);
        v += __shfl_xor(v, 4, 64);
        v += __shfl_xor(v, 8, 64);
        rinv[mt][r] = 1.0f / v;
      }
    #pragma unroll
    for (int mt = 0; mt < 2; ++mt)
      #pragma unroll
      for (int dt = 0; dt < 8; ++dt)
        #pragma unroll
        for (int r = 0; r < 4; ++r) {
          size_t row = qrowbase + wq0 + mt * 16 + quad * 4 + r;
          Ym[row * (HH * DD) + h * DD + dt * 16 + n16] = f2bf(oacc[mt][dt][r] * rinv[mt][r]);
        }
  }
}

// ---------------- launch ----------------
extern "C" void kernel_launch(void* const* d_in, const int* in_sizes, int n_in,
                              void* d_out, int out_size, void* d_ws, size_t ws_size,
                              hipStream_t stream) {
  const float* x  = (const float*)d_in[0];
  const float* Wq = (const float*)d_in[1];
  const float* Wk = (const float*)d_in[2];
  const float* Wv = (const float*)d_in[3];
  const float* Wo = (const float*)d_in[4];
  float* out = (float*)d_out;

  u16* ws   = (u16*)d_ws;
  u16* xb   = ws;                                  // 8192*2048 u16 (32 MiB)
  u16* Wbuf = xb + (size_t)8192 * 2048;            // 2048*2048 u16 (8 MiB)
  u16* Yb   = xb;                                  // alias: xb dead after QKV GEMM

  u16* ob   = (u16*)d_out;
  u16* Qb   = ob;                                                  // 32 MiB
  u16* KVb  = ob + (size_t)8192 * 2048;                            // 16 MiB
  u16* VTg  = ob + (size_t)8192 * 2048 + (size_t)8192 * 1024;      // 8 MiB
  u16* WkvT = VTg + (size_t)16 * 128 * 2048;                       // 4 MiB (1024x2048)

  cvt_f32_bf16<<<16384, 256, 0, stream>>>(x, xb, (4 * 2048 * 2048) / 4);

  transpose_w<<<dim3(64, 64), 256, 0, stream>>>(Wq, Wbuf, 2048, 2048);
  transpose_w<<<dim3(16, 64), 256, 0, stream>>>(Wk, WkvT, 2048, 512);
  transpose_w<<<dim3(16, 64), 256, 0, stream>>>(Wv, WkvT + (size_t)512 * 2048, 2048, 512);

  // fused [Q | KV] = x [Wq | Wk | Wv]  (N = 3072, BN=128: 24x32 = 768 blocks
  // = exactly 3 full dispatch rounds; the 256-wide version's 384 blocks ran
  // 256+128 with a 50%-idle tail round)
  gemm_n128<1><<<768, 512, 0, stream>>>(xb, Wbuf, WkvT, (void*)Qb, (void*)KVb,
                                        8192, 2048, 1024, 2048, 24);

  transpose_v<<<dim3(64, 4, 16), 256, 0, stream>>>(KVb, VTg);

  attn_kernel<<<dim3(8, 64), 256, 0, stream>>>(Qb, KVb, VTg, Yb);

  transpose_w<<<dim3(64, 64), 256, 0, stream>>>(Wo, Wbuf, 2048, 2048);
  gemm256<0><<<256, 512, 0, stream>>>(Yb, Wbuf, nullptr, (void*)out, nullptr,
                                      8192, 2048, 0, 2048, 8);
}

// Round 15
// 469.840 us; speedup vs baseline: 1.0727x; 1.0018x over previous
//
#include <hip/hip_runtime.h>

typedef unsigned short u16;
typedef __attribute__((ext_vector_type(8))) __bf16 bf16x8;
typedef __attribute__((ext_vector_type(4))) float f32x4;

// Problem constants
#define BB 4
#define TT 2048
#define EE 2048
#define HH 16
#define KVH 4
#define DD 128
// KVb: (B*T, 1024): cols [0,512) = K heads, [512,1024) = V heads

static __device__ __forceinline__ u16 f2bf(float f) {
  unsigned int u = __float_as_uint(f);
  u += 0x7fffu + ((u >> 16) & 1u);
  return (u16)(u >> 16);
}

// async global->LDS, 16B per lane. LDS dest is wave-uniform base + lane*16;
// all call sites pass per-lane pointers that are linear in lane with stride 16B.
static __device__ __forceinline__ void gl_lds16(const u16* g, u16* l) {
  __builtin_amdgcn_global_load_lds((__attribute__((address_space(1))) void*)g,
                                   (__attribute__((address_space(3))) void*)l,
                                   16, 0, 0);
}

// ---------------- fp32 -> bf16 convert ----------------
__global__ __launch_bounds__(256) void cvt_f32_bf16(const float* __restrict__ in,
                                                    u16* __restrict__ out, int n4) {
  int i = blockIdx.x * 256 + threadIdx.x;
  if (i >= n4) return;
  float4 v = ((const float4*)in)[i];
  union { uint2 u2; u16 s[4]; } o;
  o.s[0] = f2bf(v.x); o.s[1] = f2bf(v.y); o.s[2] = f2bf(v.z); o.s[3] = f2bf(v.w);
  ((uint2*)out)[i] = o.u2;
}

// ---------------- W (R x C) fp32 -> W^T (C x R) bf16 ----------------
__global__ __launch_bounds__(256) void transpose_w(const float* __restrict__ W,
                                                   u16* __restrict__ Wt, int R, int C) {
  __shared__ float tile[32][33];
  int tx = threadIdx.x & 31, ty = threadIdx.x >> 5;
  int r0 = blockIdx.y * 32, c0 = blockIdx.x * 32;
  #pragma unroll
  for (int i = ty; i < 32; i += 8)
    tile[i][tx] = W[(size_t)(r0 + i) * C + (c0 + tx)];
  __syncthreads();
  #pragma unroll
  for (int i = ty; i < 32; i += 8)
    Wt[(size_t)(c0 + i) * R + (r0 + tx)] = f2bf(tile[tx][i]);
}

// ---------------- V (bf16, token-major) -> VTg (d-major) ----------------
__global__ __launch_bounds__(256) void transpose_v(const u16* __restrict__ KVb,
                                                   u16* __restrict__ VTg) {
  __shared__ u16 tile[32][36];
  const int tid = threadIdx.x;
  const int t0 = blockIdx.x * 32, d0 = blockIdx.y * 32;
  const int z = blockIdx.z;                       // b*4 + kvh
  const int vb = z * 128;
  const size_t srcbase = (size_t)(z >> 2) * TT * 1024 + 512 + (z & 3) * 128;
  {
    int i = tid >> 3, c4 = (tid & 7) * 4;
    union { uint2 u; u16 s[4]; } r;
    r.u = *(const uint2*)(KVb + srcbase + (size_t)(t0 + i) * 1024 + d0 + c4);
    tile[i][c4] = r.s[0]; tile[i][c4 + 1] = r.s[1];
    tile[i][c4 + 2] = r.s[2]; tile[i][c4 + 3] = r.s[3];
  }
  __syncthreads();
  {
    int j = tid >> 3, cc = (tid & 7) * 4;
    union { uint2 u; u16 s[4]; } w;
    w.s[0] = tile[cc][j]; w.s[1] = tile[cc + 1][j];
    w.s[2] = tile[cc + 2][j]; w.s[3] = tile[cc + 3][j];
    *(uint2*)(VTg + (size_t)(vb + d0 + j) * TT + t0 + cc) = w.u;
  }
}

// ---------------- 256x128 4-phase bf16 GEMM, BK=64 (QKV projection) -------
// (unchanged from R14 — part of the measured 470.7 µs configuration)
// 8 waves as 4(mi) x 2(ni) over 64x64 sub-tiles; LDS 96 KiB (1 block/CU);
// 768 blocks = 3 full dispatch rounds; counted vmcnt(2).
template <int MODE>
__global__ __launch_bounds__(512) void gemm_n128(const u16* __restrict__ A,
                                                 const u16* __restrict__ Bt0,
                                                 const u16* __restrict__ Bt1,
                                                 void* __restrict__ C0,
                                                 void* __restrict__ C1,
                                                 int M, int N0, int N1, int K, int nbx) {
  __shared__ __align__(16) u16 sh[2][3][8192];  // [buf][A0,A1,B][128*64]
  const int tid = threadIdx.x;
  const int lane = tid & 63, wave = tid >> 6;
  const int quad = lane >> 4, n16 = lane & 15;
  const int mi = wave >> 1, ni = wave & 1;      // 4 x 2 waves, 64x64 each

  const int nwg = gridDim.x;
  int wg = blockIdx.x;
  wg = (wg & 7) * (nwg >> 3) + (wg >> 3);       // bijective: nwg % 8 == 0
  const int bx = wg % nbx, by = wg / nbx;
  const size_t rowbase = (size_t)by * 256;
  const int colbase = bx * 128;

  const u16* Bt = Bt0;
  int bcol = colbase;
  if (MODE == 1 && colbase >= N0) { Bt = Bt1; bcol = colbase - N0; }

  // staging: A-half = 128x64 u16 = 1024 chunks of 16B (2 loads/thread);
  // B tile = 128x64 = 1024 chunks (2 loads/thread). inverse XOR-8 swizzle
  // on the global source, linear LDS dest (rule 21 both-sides).
  const int c0 = tid, c1 = tid + 512;
  const int r0s = c0 >> 3, ci0 = (c0 & 7) ^ (r0s & 7);
  const int r1s = c1 >> 3, ci1 = (c1 & 7) ^ (r1s & 7);
  const u16* Ag0 = A + (rowbase + r0s) * (size_t)K + ci0 * 8;
  const u16* Ag1 = A + (rowbase + r1s) * (size_t)K + ci1 * 8;
  const u16* Bg0 = Bt + ((size_t)bcol + r0s) * K + ci0 * 8;
  const u16* Bg1 = Bt + ((size_t)bcol + r1s) * K + ci1 * 8;
  const size_t h128K = (size_t)128 * K;

#define STAGEN(ob, h, kb) do {                                             \
    if ((h) < 2) {                                                         \
      gl_lds16(Ag0 + (size_t)(h) * h128K + (kb), &sh[ob][h][c0 * 8]);      \
      gl_lds16(Ag1 + (size_t)(h) * h128K + (kb), &sh[ob][h][c1 * 8]);      \
    } else {                                                               \
      gl_lds16(Bg0 + (kb), &sh[ob][2][c0 * 8]);                            \
      gl_lds16(Bg1 + (kb), &sh[ob][2][c1 * 8]);                            \
    } } while (0)

#define LDAN(mh) do {                                                      \
    _Pragma("unroll") for (int m = 0; m < 2; ++m)                          \
      _Pragma("unroll") for (int kk = 0; kk < 2; ++kk) {                   \
        int row_ = (mi & 1) * 64 + ((mh) * 2 + m) * 16 + n16;              \
        int c_ = row_ * 8 + ((kk * 4 + quad) ^ (n16 & 7));                 \
        af[m][kk] = *(const bf16x8*)&sh[buf][mi >> 1][c_ * 8];             \
      } } while (0)

#define LDBN(nh, BF) do {                                                  \
    _Pragma("unroll") for (int n = 0; n < 2; ++n)                          \
      _Pragma("unroll") for (int kk = 0; kk < 2; ++kk) {                   \
        int row_ = ni * 64 + ((nh) * 2 + n) * 16 + n16;                    \
        int c_ = row_ * 8 + ((kk * 4 + quad) ^ (n16 & 7));                 \
        BF[n][kk] = *(const bf16x8*)&sh[buf][2][c_ * 8];                   \
      } } while (0)

#define QUADN(mh, nh, BF) do {                                             \
    __builtin_amdgcn_s_setprio(1);                                         \
    _Pragma("unroll") for (int m = 0; m < 2; ++m)                          \
      _Pragma("unroll") for (int n = 0; n < 2; ++n)                        \
        _Pragma("unroll") for (int kk = 0; kk < 2; ++kk)                   \
          acc[(mh) * 2 + m][(nh) * 2 + n] =                                \
              __builtin_amdgcn_mfma_f32_16x16x32_bf16(                     \
                  af[m][kk], BF[n][kk], acc[(mh) * 2 + m][(nh) * 2 + n],   \
                  0, 0, 0);                                                \
    __builtin_amdgcn_s_setprio(0);                                         \
  } while (0)

#define FENCE() asm volatile("" ::: "memory")

  f32x4 acc[4][4];
  #pragma unroll
  for (int i = 0; i < 4; ++i)
    #pragma unroll
    for (int j = 0; j < 4; ++j) acc[i][j] = (f32x4){0.f, 0.f, 0.f, 0.f};

  bf16x8 af[2][2], bf0[2][2], bf1[2][2];
  const int nt = K / 64;

  STAGEN(0, 0, 0); STAGEN(0, 1, 0); STAGEN(0, 2, 0);

  #pragma unroll 2
  for (int t = 0; t < nt; ++t) {
    const int buf = t & 1, ob = buf ^ 1;
    const int kbn = (t + 1) * 64;
    const bool pre = (t + 1 < nt);

    // at top: 6 loads of tile t outstanding; issue 2 (t+1 A0) -> 8;
    // vmcnt(2) drains the oldest 6 (tile t complete), keeps 2 in flight.
    if (pre) {
      STAGEN(ob, 0, kbn);
      asm volatile("s_waitcnt vmcnt(2)" ::: "memory");
    } else {
      asm volatile("s_waitcnt vmcnt(0)" ::: "memory");
    }
    __builtin_amdgcn_s_barrier(); FENCE();
    LDAN(0); LDBN(0, bf0);
    QUADN(0, 0, bf0);
    __builtin_amdgcn_s_barrier(); FENCE();

    LDBN(1, bf1);
    if (pre) STAGEN(ob, 1, kbn);
    __builtin_amdgcn_s_barrier(); FENCE();
    QUADN(0, 1, bf1);
    __builtin_amdgcn_s_barrier(); FENCE();

    LDAN(1);
    if (pre) STAGEN(ob, 2, kbn);
    __builtin_amdgcn_s_barrier(); FENCE();
    QUADN(1, 1, bf1);
    __builtin_amdgcn_s_barrier(); FENCE();

    __builtin_amdgcn_s_barrier(); FENCE();
    QUADN(1, 0, bf0);
    __builtin_amdgcn_s_barrier(); FENCE();
  }

#undef STAGEN
#undef LDAN
#undef LDBN
#undef QUADN
#undef FENCE

  const size_t crow0 = rowbase + (size_t)mi * 64;
  #pragma unroll
  for (int mt = 0; mt < 4; ++mt) {
    #pragma unroll
    for (int r = 0; r < 4; ++r) {
      size_t row = crow0 + mt * 16 + quad * 4 + r;
      #pragma unroll
      for (int nt_ = 0; nt_ < 4; ++nt_) {
        int col = colbase + ni * 64 + nt_ * 16 + n16;
        float v = acc[mt][nt_][r];
        if (MODE == 0) {
          ((float*)C0)[row * (size_t)N0 + col] = v;
        } else {
          if (col < N0) ((u16*)C0)[row * (size_t)N0 + col] = f2bf(v);
          else          ((u16*)C1)[row * (size_t)N1 + (col - N0)] = f2bf(v);
        }
      }
    }
  }
}

// ---------------- 256x128 bf16 GEMM, BK=32, 2 blocks/CU (out-projection) ---
// Round-15: occupancy fix for the stall-bound out-GEMM (measured ~145 µs ≈
// 475 TF vs MFMA floor 8 µs and L2-feed floor ~23 µs -> stalls dominate at
// 1 block/CU). LDS 48 KiB + __launch_bounds__(512,4) (VGPR<=128) -> 2
// blocks/CU; grid 16x32 = 512 = exactly 2/CU, one round. Per tile: 3
// gl_lds/thread (A0,A1,B one 16B chunk each), counted vmcnt(3), 2 barriers,
// 16 MFMA. Swizzle for 4-chunk rows: source ci=(c&3)^((c>>3)&3); read
// chunk=row*4+(quad^((row>>1)&3)) — involution, worst-case 2-way (free).
__global__ __launch_bounds__(512, 4) void gemm_k32(const u16* __restrict__ A,
                                                   const u16* __restrict__ Bt,
                                                   float* __restrict__ C,
                                                   int M, int N, int K, int nbx) {
  __shared__ __align__(16) u16 sh[2][3][4096];  // [buf][A0,A1,B][128*32]
  const int tid = threadIdx.x;
  const int lane = tid & 63, wave = tid >> 6;
  const int quad = lane >> 4, n16 = lane & 15;
  const int mi = wave >> 1, ni = wave & 1;      // 4 x 2 waves, 64x64 each

  const int nwg = gridDim.x;
  int wg = blockIdx.x;
  wg = (wg & 7) * (nwg >> 3) + (wg >> 3);       // bijective: nwg % 8 == 0
  const int bx = wg % nbx, by = wg / nbx;
  const size_t rowbase = (size_t)by * 256;
  const int colbase = bx * 128;

  // staging: 3 slots x 512 chunks of 16B; thread stages chunk `tid` of each.
  // chunk c holds global (row=c>>2, ci=(c&3)^((c>>3)&3)); LDS dest linear.
  const int srow = tid >> 2, sci = (tid & 3) ^ ((tid >> 3) & 3);
  const u16* Ag0 = A + (rowbase + srow) * (size_t)K + sci * 8;
  const u16* Ag1 = A + (rowbase + 128 + srow) * (size_t)K + sci * 8;
  const u16* Bg  = Bt + ((size_t)colbase + srow) * K + sci * 8;

#define STAGEK(ob, kb) do {                                                \
    gl_lds16(Ag0 + (kb), &sh[ob][0][tid * 8]);                             \
    gl_lds16(Ag1 + (kb), &sh[ob][1][tid * 8]);                             \
    gl_lds16(Bg  + (kb), &sh[ob][2][tid * 8]);                             \
  } while (0)

#define FENCE() asm volatile("" ::: "memory")

  f32x4 acc[4][4];
  #pragma unroll
  for (int i = 0; i < 4; ++i)
    #pragma unroll
    for (int j = 0; j < 4; ++j) acc[i][j] = (f32x4){0.f, 0.f, 0.f, 0.f};

  const int nt = K / 32;                        // 64 K-tiles
  STAGEK(0, 0);

  #pragma unroll 2
  for (int t = 0; t < nt; ++t) {
    const int buf = t & 1, ob = buf ^ 1;
    if (t + 1 < nt) {
      STAGEK(ob, (t + 1) * 32);
      asm volatile("s_waitcnt vmcnt(3)" ::: "memory"); // tile t's 3 landed
    } else {
      asm volatile("s_waitcnt vmcnt(0)" ::: "memory"); // tail drain
    }
    __builtin_amdgcn_s_barrier(); FENCE();

    bf16x8 af[4], bf[4];
    #pragma unroll
    for (int m = 0; m < 4; ++m) {
      int row_ = (mi & 1) * 64 + m * 16 + n16;
      int c_ = row_ * 4 + (quad ^ ((row_ >> 1) & 3));
      af[m] = *(const bf16x8*)&sh[buf][mi >> 1][c_ * 8];
    }
    #pragma unroll
    for (int n = 0; n < 4; ++n) {
      int row_ = ni * 64 + n * 16 + n16;
      int c_ = row_ * 4 + (quad ^ ((row_ >> 1) & 3));
      bf[n] = *(const bf16x8*)&sh[buf][2][c_ * 8];
    }

    __builtin_amdgcn_s_setprio(1);
    #pragma unroll
    for (int m = 0; m < 4; ++m)
      #pragma unroll
      for (int n = 0; n < 4; ++n)
        acc[m][n] = __builtin_amdgcn_mfma_f32_16x16x32_bf16(af[m], bf[n], acc[m][n], 0, 0, 0);
    __builtin_amdgcn_s_setprio(0);

    FENCE(); __builtin_amdgcn_s_barrier(); FENCE();
  }

#undef STAGEK
#undef FENCE

  const size_t crow0 = rowbase + (size_t)mi * 64;
  #pragma unroll
  for (int mt = 0; mt < 4; ++mt) {
    #pragma unroll
    for (int r = 0; r < 4; ++r) {
      size_t row = crow0 + mt * 16 + quad * 4 + r;
      #pragma unroll
      for (int nt_ = 0; nt_ < 4; ++nt_) {
        int col = colbase + ni * 64 + nt_ * 16 + n16;
        C[row * (size_t)N + col] = acc[mt][nt_][r];
      }
    }
  }
}

// ---------------- flash attention (causal, GQA), no-max softmax ------------
// R10-exact (measured 148.7/149.9 µs @ 20.2% occ, VGPR 112): 128 q-rows/block,
// balanced 2-pass grid (8,64); f2bf scalar casts, ternary mask, s_waitcnt(0)
// P-wait, single-buffer + __syncthreads; Vt XOR swizzle (conflicts 5.57M->1.1M).
__global__ __launch_bounds__(256) void attn_kernel(const u16* __restrict__ Qm,
                                                   const u16* __restrict__ KVm,
                                                   const u16* __restrict__ VTg,
                                                   u16* __restrict__ Ym) {
  __shared__ u16 Ks[32 * 128];
  __shared__ u16 Vt[128 * 32];
  __shared__ u16 Pb[4 * 32 * 40];

  const int tid = threadIdx.x;
  const int lane = tid & 63, wave = tid >> 6;
  const int quad = lane >> 4, n16 = lane & 15;
  const int b = blockIdx.y >> 4, h = blockIdx.y & 15;
  const int kvh = h >> 2;
  const int kvbase = b * TT;
  const u16* VTg_ = VTg + (size_t)((b * 4 + kvh) * 128) * TT;

  // K staging: XOR-16 chunk swizzle (conflict-free verified)
  const int krow = tid >> 4, kslot = tid & 15;
  const int kg = (kslot ^ krow) * 8;
  u16* Ksd0 = &Ks[krow * 128 + kslot * 8];      // byte = tid*16 (linear dest)
  u16* Ksd1 = &Ks[(krow + 16) * 128 + kslot * 8];
  // V staging: swizzle ci^((row>>1)&3); linear LDS dest, source carries swizzle.
  const int vrow = tid >> 2, vs = tid & 3;
  const int vq8 = (vs ^ ((tid >> 3) & 3)) * 8;
  u16* Vtd0 = &Vt[vrow * 32 + vs * 8];
  u16* Vtd1 = &Vt[(vrow + 64) * 32 + vs * 8];

  constexpr float SCL = 0.08838834764831843f * 1.4426950408889634f;

  for (int pass = 0; pass < 2; ++pass) {
    const int qt = pass ? 15 - (int)blockIdx.x : (int)blockIdx.x;
    const int q0 = qt * 128;
    const size_t qrowbase = (size_t)(b * TT + q0);
    const int wq0 = wave * 32;

    bf16x8 aq[2][4];
    #pragma unroll
    for (int mt = 0; mt < 2; ++mt) {
      const u16* qp = Qm + (qrowbase + wq0 + mt * 16 + n16) * (HH * DD) + h * DD + quad * 8;
      #pragma unroll
      for (int dt = 0; dt < 4; ++dt)
        aq[mt][dt] = *(const bf16x8*)(qp + dt * 32);
    }

    float lrow[2][4];
    f32x4 oacc[2][8];
    #pragma unroll
    for (int mt = 0; mt < 2; ++mt) {
      #pragma unroll
      for (int r = 0; r < 4; ++r) lrow[mt][r] = 0.f;
      #pragma unroll
      for (int i = 0; i < 8; ++i) oacc[mt][i] = (f32x4){0.f, 0.f, 0.f, 0.f};
    }

    const int kend = q0 + 128;
    for (int kb = 0; kb < kend; kb += 32) {
      __syncthreads();
      gl_lds16(KVm + (size_t)(kvbase + kb + krow) * 1024 + kvh * DD + kg, Ksd0);
      gl_lds16(KVm + (size_t)(kvbase + kb + krow + 16) * 1024 + kvh * DD + kg, Ksd1);
      gl_lds16(VTg_ + (size_t)vrow * TT + kb + vq8, Vtd0);
      gl_lds16(VTg_ + (size_t)(vrow + 64) * TT + kb + vq8, Vtd1);
      __syncthreads();

      // S = Q K^T : 2 m-tiles x 2 key-halves, K-frags shared across m
      f32x4 sf[2][2];
      #pragma unroll
      for (int half = 0; half < 2; ++half) {
        bf16x8 bk[4];
        #pragma unroll
        for (int dt = 0; dt < 4; ++dt) {
          int slot = (dt * 4 + quad) ^ n16;   // un-swizzle
          bk[dt] = *(const bf16x8*)&Ks[(half * 16 + n16) * 128 + slot * 8];
        }
        #pragma unroll
        for (int mt = 0; mt < 2; ++mt) {
          f32x4 s = (f32x4){0.f, 0.f, 0.f, 0.f};
          #pragma unroll
          for (int dt = 0; dt < 4; ++dt)
            s = __builtin_amdgcn_mfma_f32_16x16x32_bf16(aq[mt][dt], bk[dt], s, 0, 0, 0);
          sf[mt][half] = s;
        }
      }

      // p = exp2(s*scale*log2e) with causal mask; accumulate per-lane l; stash P
      u16* pw = &Pb[wave * (32 * 40)];
      #pragma unroll
      for (int mt = 0; mt < 2; ++mt)
        #pragma unroll
        for (int half = 0; half < 2; ++half) {
          int key = kb + half * 16 + n16;
          #pragma unroll
          for (int r = 0; r < 4; ++r) {
            int qpos = q0 + wq0 + mt * 16 + quad * 4 + r;
            float pv = (key <= qpos) ? exp2f(sf[mt][half][r] * SCL) : 0.f;
            lrow[mt][r] += pv;
            pw[(mt * 16 + quad * 4 + r) * 40 + half * 16 + n16] = f2bf(pv);
          }
        }
      __builtin_amdgcn_s_waitcnt(0);  // drain ds_writes before same-wave cross-lane read
      bf16x8 ap[2];
      ap[0] = *(const bf16x8*)&pw[n16 * 40 + quad * 8];
      ap[1] = *(const bf16x8*)&pw[(16 + n16) * 40 + quad * 8];

      // O += P V : V-frags shared across m-tiles (swizzled read)
      #pragma unroll
      for (int dt = 0; dt < 8; ++dt) {
        bf16x8 bv = *(const bf16x8*)&Vt[(dt * 16 + n16) * 32 +
                                        ((quad ^ ((n16 >> 1) & 3)) * 8)];
        oacc[0][dt] = __builtin_amdgcn_mfma_f32_16x16x32_bf16(ap[0], bv, oacc[0][dt], 0, 0, 0);
        oacc[1][dt] = __builtin_amdgcn_mfma_f32_16x16x32_bf16(ap[1], bv, oacc[1][dt], 0, 0, 0);
      }
    }

    // epilogue: reduce l across the 16 key-lanes, normalize, store
    float rinv[2][4];
    #pragma unroll
    for (int mt = 0; mt < 2; ++mt)
      #pragma unroll
      for (int r = 0; r < 4; ++r) {
        float v = lrow[mt][r];
        v += __shfl_xor(v, 1, 64);
        v += __shfl_xor(v, 2, 64);
        v += __shfl_xor(v, 4, 64);
        v += __shfl_xor(v, 8, 64);
        rinv[mt][r] = 1.0f / v;
      }
    #pragma unroll
    for (int mt = 0; mt < 2; ++mt)
      #pragma unroll
      for (int dt = 0; dt < 8; ++dt)
        #pragma unroll
        for (int r = 0; r < 4; ++r) {
          size_t row = qrowbase + wq0 + mt * 16 + quad * 4 + r;
          Ym[row * (HH * DD) + h * DD + dt * 16 + n16] = f2bf(oacc[mt][dt][r] * rinv[mt][r]);
        }
  }
}

// ---------------- launch ----------------
extern "C" void kernel_launch(void* const* d_in, const int* in_sizes, int n_in,
                              void* d_out, int out_size, void* d_ws, size_t ws_size,
                              hipStream_t stream) {
  const float* x  = (const float*)d_in[0];
  const float* Wq = (const float*)d_in[1];
  const float* Wk = (const float*)d_in[2];
  const float* Wv = (const float*)d_in[3];
  const float* Wo = (const float*)d_in[4];
  float* out = (float*)d_out;

  u16* ws   = (u16*)d_ws;
  u16* xb   = ws;                                  // 8192*2048 u16 (32 MiB)
  u16* Wbuf = xb + (size_t)8192 * 2048;            // 2048*2048 u16 (8 MiB)
  u16* Yb   = xb;                                  // alias: xb dead after QKV GEMM

  u16* ob   = (u16*)d_out;
  u16* Qb   = ob;                                                  // 32 MiB
  u16* KVb  = ob + (size_t)8192 * 2048;                            // 16 MiB
  u16* VTg  = ob + (size_t)8192 * 2048 + (size_t)8192 * 1024;      // 8 MiB
  u16* WkvT = VTg + (size_t)16 * 128 * 2048;                       // 4 MiB (1024x2048)

  cvt_f32_bf16<<<16384, 256, 0, stream>>>(x, xb, (4 * 2048 * 2048) / 4);

  transpose_w<<<dim3(64, 64), 256, 0, stream>>>(Wq, Wbuf, 2048, 2048);
  transpose_w<<<dim3(16, 64), 256, 0, stream>>>(Wk, WkvT, 2048, 512);
  transpose_w<<<dim3(16, 64), 256, 0, stream>>>(Wv, WkvT + (size_t)512 * 2048, 2048, 512);

  // fused [Q | KV] = x [Wq | Wk | Wv]  (N = 3072, BN=128: 768 blocks)
  gemm_n128<1><<<768, 512, 0, stream>>>(xb, Wbuf, WkvT, (void*)Qb, (void*)KVb,
                                        8192, 2048, 1024, 2048, 24);

  transpose_v<<<dim3(64, 4, 16), 256, 0, stream>>>(KVb, VTg);

  attn_kernel<<<dim3(8, 64), 256, 0, stream>>>(Qb, KVb, VTg, Yb);

  // out = Y Wo  (BK=32, 2 blocks/CU: grid 16x32 = 512 = exactly 2/CU)
  transpose_w<<<dim3(64, 64), 256, 0, stream>>>(Wo, Wbuf, 2048, 2048);
  gemm_k32<<<512, 512, 0, stream>>>(Yb, Wbuf, out, 8192, 2048, 2048, 16);
}